// Round 1
// baseline (83.158 us; speedup 1.0000x reference)
//
#include <hip/hip_runtime.h>

// m_ij = MLP([dist, dist^-3]) is a scalar function of s = |r|^2 + eps^2 only.
// Kernel 1 tabulates m(s) at float-bit sample points (6 mantissa bits x 22
// octaves, s in [2^-14, 2^8]) and zeroes d_out. Kernel 2 does symmetric
// all-pairs acc[i] = sum_j m(s_ij)*(p_j - p_i)  (j==i term is exactly 0),
// evaluating m via a per-interval (slope,intercept) LDS table: one
// ds_read_b64 gather + one fma per pair. p_j is wave-uniform -> scalar loads.
// R7: NSPLIT 32->64 (512 blocks = 2/CU = 4 waves/SIMD). Theory: forces is
// latency-bound at 2 waves/SIMD (dep chain sub->fma^3->idx->ds_read->fma with
// only 2-way TLP); doubling resident waves halves exposed latency. Work is
// unchanged; staging dupes (+0.2us L2) and atomics (786K ops) stay negligible.

#define EPS2      1.0e-4f
#define TAB_BITS  6
#define TAB_SHIFT (23 - TAB_BITS)            // 17
#define TAB_EMIN  113                        // biased exponent of 2^-14
#define TAB_BASE  (TAB_EMIN << TAB_BITS)     // 7232
#define TAB_OCT   22                         // 2^-14 .. 2^8
#define TAB_N     (TAB_OCT << TAB_BITS)      // 1408 intervals

#define NPART  2048
#define BLOCK  512
#define CHUNK  512                           // i-particles per block
#define NSPLIT 64                            // j-range splits (512 blocks = 2/CU)
#define JPT    (NPART / NSPLIT)              // 32 j per block's range

// ---- table build: 64 threads/entry, one output channel per lane ----------
// W2[k*64 + lane] is a coalesced 256B/wave load; W1/b1 are wave-uniform.
__global__ void build_table(const float* __restrict__ W1, const float* __restrict__ b1,
                            const float* __restrict__ W2, const float* __restrict__ b2,
                            const float* __restrict__ W3, const float* __restrict__ b3,
                            float* __restrict__ tab, float* __restrict__ out, int out_n) {
    const int t = blockIdx.x * blockDim.x + threadIdx.x;

    if (t < out_n) out[t] = 0.0f;            // harness poisons d_out to 0xAA

    const int entry = t >> 6;
    const int o     = t & 63;                // output channel == lane
    if (entry > TAB_N) return;

    const unsigned u = (unsigned)(entry + TAB_BASE) << TAB_SHIFT;
    const float s = __uint_as_float(u);      // exact sample point
    const float d = sqrtf(s);
    const float idc = 1.0f / (s * d);

    float acc = b2[o];
#pragma unroll
    for (int k = 0; k < 64; ++k) {
        float hv = fmaf(d, W1[k], fmaf(idc, W1[64 + k], b1[k]));
        hv = hv > 0.0f ? hv : 0.0f;
        acc = fmaf(hv, W2[k * 64 + o], acc);
    }
    float part = (acc > 0.0f ? acc : 0.0f) * W3[o];

    part += __shfl_down(part, 32, 64);
    part += __shfl_down(part, 16, 64);
    part += __shfl_down(part, 8, 64);
    part += __shfl_down(part, 4, 64);
    part += __shfl_down(part, 2, 64);
    part += __shfl_down(part, 1, 64);
    if (o == 0) tab[entry] = part + b3[0];
}

// ---------------- all-pairs force accumulation -----------------------------
__global__ __launch_bounds__(BLOCK, 4)
void forces(const float* __restrict__ pos, const float* __restrict__ tab,
            float* __restrict__ out) {
    __shared__ float2 tabs[TAB_N + 1];       // (slope, intercept): 11272 B

    const int tid = threadIdx.x;

    // stage table as (a,b): m(s) = a*s + b on each interval. Interval width
    // is an exact power of 2 -> reciprocal by exponent arithmetic.
    for (int k = tid; k < TAB_N; k += BLOCK) {
        float t0 = tab[k], t1 = tab[k + 1];
        float s0 = __uint_as_float((unsigned)(k + TAB_BASE) << TAB_SHIFT);
        float rcpw = __uint_as_float((unsigned)(147 - (k >> TAB_BITS)) << 23);
        float a = (t1 - t0) * rcpw;
        tabs[k] = make_float2(a, fmaf(-a, s0, t0));
    }
    __syncthreads();

    const int split = blockIdx.x;
    const int chunk = blockIdx.y;
    const int b     = blockIdx.z;

    const float* posb = pos + (size_t)b * NPART * 3;
    const int i = chunk * CHUNK + tid;
    const float pix = posb[i * 3 + 0];
    const float piy = posb[i * 3 + 1];
    const float piz = posb[i * 3 + 2];

    float ax = 0.0f, ay = 0.0f, az = 0.0f;
    const float* pj = posb + split * JPT * 3;    // wave-uniform -> s_load

#pragma unroll 8
    for (int jj = 0; jj < JPT; ++jj) {
        float dx = pj[jj * 3 + 0] - pix;
        float dy = pj[jj * 3 + 1] - piy;
        float dz = pj[jj * 3 + 2] - piz;
        float s = fmaf(dx, dx, fmaf(dy, dy, fmaf(dz, dz, EPS2)));
        // s >= EPS2 = 1e-4 > 2^-14 so no underflow; unsigned min clamps high.
        unsigned idx = (__float_as_uint(s) >> TAB_SHIFT) - TAB_BASE;
        idx = idx > TAB_N - 1u ? TAB_N - 1u : idx;
        float2 ab = tabs[idx];                   // one ds_read_b64 gather
        float m = fmaf(s, ab.x, ab.y);
        ax = fmaf(m, dx, ax);
        ay = fmaf(m, dy, ay);
        az = fmaf(m, dz, az);
    }

    float* o = out + ((size_t)b * NPART + i) * 3;
    atomicAdd(o + 0, ax);
    atomicAdd(o + 1, ay);
    atomicAdd(o + 2, az);
}

extern "C" void kernel_launch(void* const* d_in, const int* in_sizes, int n_in,
                              void* d_out, int out_size, void* d_ws, size_t ws_size,
                              hipStream_t stream) {
    const float* pos = (const float*)d_in[0];
    const float* W1  = (const float*)d_in[1];
    const float* b1  = (const float*)d_in[2];
    const float* W2  = (const float*)d_in[3];
    const float* b2  = (const float*)d_in[4];
    const float* W3  = (const float*)d_in[5];
    const float* b3  = (const float*)d_in[6];
    float* out = (float*)d_out;
    float* tab = (float*)d_ws;               // (TAB_N+1) floats

    const int B = in_sizes[0] / (NPART * 3); // = 2

    const int build_threads = (TAB_N + 1) * 64;  // 90176 >= out_size (12288)
    build_table<<<(build_threads + 255) / 256, 256, 0, stream>>>(
        W1, b1, W2, b2, W3, b3, tab, out, out_size);

    forces<<<dim3(NSPLIT, NPART / CHUNK, B), BLOCK, 0, stream>>>(pos, tab, out);
}

// Round 2
// 76.850 us; speedup vs baseline: 1.0821x; 1.0821x over previous
//
#include <hip/hip_runtime.h>

// m_ij = MLP([dist, dist^-3]) is a scalar function of s = |r|^2 + eps^2 only.
// Kernel 1 tabulates m(s) at float-bit sample points (6 mantissa bits x 22
// octaves, s in [2^-14, 2^8]) and zeroes d_out. Kernel 2 does symmetric
// all-pairs acc[i] = sum_j m(s_ij)*(p_j - p_i)  (j==i term is exactly 0),
// evaluating m via a per-interval (slope,intercept) LDS table: one
// ds_read_b64 gather + one fma per pair. p_j is wave-uniform -> scalar loads.
// R7 FAILED: NSPLIT 32->64 regressed +5.3us -> kernel time scales with NSPLIT.
// What scales with NSPLIT is atomic traffic (12288 addrs x NSPLIT serialized
// RMWs at the memory-side cache). R8: drop atomics -- forces stores per-split
// partials to d_ws (contention-free coalesced stores), new reduce kernel sums
// NSPLIT partials per output (1.6MB L2-hot, ~1-2us). NSPLIT back to 32.

#define EPS2      1.0e-4f
#define TAB_BITS  6
#define TAB_SHIFT (23 - TAB_BITS)            // 17
#define TAB_EMIN  113                        // biased exponent of 2^-14
#define TAB_BASE  (TAB_EMIN << TAB_BITS)     // 7232
#define TAB_OCT   22                         // 2^-14 .. 2^8
#define TAB_N     (TAB_OCT << TAB_BITS)      // 1408 intervals

#define NPART  2048
#define BLOCK  512
#define CHUNK  512                           // i-particles per block
#define NSPLIT 32                            // j-range splits (256 blocks = 1/CU)
#define JPT    (NPART / NSPLIT)              // 64 j per block's range
#define PART_OFF 2048                        // float offset of partials in d_ws

// ---- table build: 64 threads/entry, one output channel per lane ----------
// W2[k*64 + lane] is a coalesced 256B/wave load; W1/b1 are wave-uniform.
__global__ void build_table(const float* __restrict__ W1, const float* __restrict__ b1,
                            const float* __restrict__ W2, const float* __restrict__ b2,
                            const float* __restrict__ W3, const float* __restrict__ b3,
                            float* __restrict__ tab, float* __restrict__ out, int out_n) {
    const int t = blockIdx.x * blockDim.x + threadIdx.x;

    if (t < out_n) out[t] = 0.0f;            // harness poisons d_out to 0xAA

    const int entry = t >> 6;
    const int o     = t & 63;                // output channel == lane
    if (entry > TAB_N) return;

    const unsigned u = (unsigned)(entry + TAB_BASE) << TAB_SHIFT;
    const float s = __uint_as_float(u);      // exact sample point
    const float d = sqrtf(s);
    const float idc = 1.0f / (s * d);

    float acc = b2[o];
#pragma unroll
    for (int k = 0; k < 64; ++k) {
        float hv = fmaf(d, W1[k], fmaf(idc, W1[64 + k], b1[k]));
        hv = hv > 0.0f ? hv : 0.0f;
        acc = fmaf(hv, W2[k * 64 + o], acc);
    }
    float part = (acc > 0.0f ? acc : 0.0f) * W3[o];

    part += __shfl_down(part, 32, 64);
    part += __shfl_down(part, 16, 64);
    part += __shfl_down(part, 8, 64);
    part += __shfl_down(part, 4, 64);
    part += __shfl_down(part, 2, 64);
    part += __shfl_down(part, 1, 64);
    if (o == 0) tab[entry] = part + b3[0];
}

// ---------------- all-pairs force accumulation -----------------------------
__global__ __launch_bounds__(BLOCK, 4)
void forces(const float* __restrict__ pos, const float* __restrict__ tab,
            float* __restrict__ part) {
    __shared__ float2 tabs[TAB_N + 1];       // (slope, intercept): 11272 B

    const int tid = threadIdx.x;

    // stage table as (a,b): m(s) = a*s + b on each interval. Interval width
    // is an exact power of 2 -> reciprocal by exponent arithmetic.
    for (int k = tid; k < TAB_N; k += BLOCK) {
        float t0 = tab[k], t1 = tab[k + 1];
        float s0 = __uint_as_float((unsigned)(k + TAB_BASE) << TAB_SHIFT);
        float rcpw = __uint_as_float((unsigned)(147 - (k >> TAB_BITS)) << 23);
        float a = (t1 - t0) * rcpw;
        tabs[k] = make_float2(a, fmaf(-a, s0, t0));
    }
    __syncthreads();

    const int split = blockIdx.x;
    const int chunk = blockIdx.y;
    const int b     = blockIdx.z;

    const float* posb = pos + (size_t)b * NPART * 3;
    const int i = chunk * CHUNK + tid;
    const float pix = posb[i * 3 + 0];
    const float piy = posb[i * 3 + 1];
    const float piz = posb[i * 3 + 2];

    float ax = 0.0f, ay = 0.0f, az = 0.0f;
    const float* pj = posb + split * JPT * 3;    // wave-uniform -> s_load

#pragma unroll 8
    for (int jj = 0; jj < JPT; ++jj) {
        float dx = pj[jj * 3 + 0] - pix;
        float dy = pj[jj * 3 + 1] - piy;
        float dz = pj[jj * 3 + 2] - piz;
        float s = fmaf(dx, dx, fmaf(dy, dy, fmaf(dz, dz, EPS2)));
        // s >= EPS2 = 1e-4 > 2^-14 so no underflow; unsigned min clamps high.
        unsigned idx = (__float_as_uint(s) >> TAB_SHIFT) - TAB_BASE;
        idx = idx > TAB_N - 1u ? TAB_N - 1u : idx;
        float2 ab = tabs[idx];                   // one ds_read_b64 gather
        float m = fmaf(s, ab.x, ab.y);
        ax = fmaf(m, dx, ax);
        ay = fmaf(m, dy, ay);
        az = fmaf(m, dz, az);
    }

    // contention-free partial store: part[((b*NSPLIT+split)*NPART + i)*3 + c]
    float* po = part + ((size_t)(b * NSPLIT + split) * NPART + i) * 3;
    po[0] = ax;
    po[1] = ay;
    po[2] = az;
}

// ---------------- partial reduction: out[e] = sum_split part ---------------
__global__ void reduce_partials(const float* __restrict__ part,
                                float* __restrict__ out, int total) {
    const int e = blockIdx.x * blockDim.x + threadIdx.x;  // e in [0, B*NPART*3)
    if (e >= total) return;
    const int b = e / (NPART * 3);
    const int r = e - b * (NPART * 3);
    const float* p = part + (size_t)b * NSPLIT * NPART * 3 + r;
    float s = 0.0f;
#pragma unroll
    for (int k = 0; k < NSPLIT; ++k) s += p[(size_t)k * NPART * 3];
    out[e] = s;
}

extern "C" void kernel_launch(void* const* d_in, const int* in_sizes, int n_in,
                              void* d_out, int out_size, void* d_ws, size_t ws_size,
                              hipStream_t stream) {
    const float* pos = (const float*)d_in[0];
    const float* W1  = (const float*)d_in[1];
    const float* b1  = (const float*)d_in[2];
    const float* W2  = (const float*)d_in[3];
    const float* b2  = (const float*)d_in[4];
    const float* W3  = (const float*)d_in[5];
    const float* b3  = (const float*)d_in[6];
    float* out  = (float*)d_out;
    float* tab  = (float*)d_ws;              // (TAB_N+1) floats
    float* part = (float*)d_ws + PART_OFF;   // B*NSPLIT*NPART*3 floats (1.57 MB)

    const int B = in_sizes[0] / (NPART * 3); // = 2

    const int build_threads = (TAB_N + 1) * 64;  // 90176 >= out_size (12288)
    build_table<<<(build_threads + 255) / 256, 256, 0, stream>>>(
        W1, b1, W2, b2, W3, b3, tab, out, out_size);

    forces<<<dim3(NSPLIT, NPART / CHUNK, B), BLOCK, 0, stream>>>(pos, tab, part);

    const int total = B * NPART * 3;         // 12288
    reduce_partials<<<(total + 255) / 256, 256, 0, stream>>>(part, out, total);
}

// Round 3
// 74.788 us; speedup vs baseline: 1.1119x; 1.0276x over previous
//
#include <hip/hip_runtime.h>

// m_ij = MLP([dist, dist^-3]) is a scalar function of s = |r|^2 + eps^2 only.
// Kernel 1 tabulates m(s) at float-bit sample points (6 mantissa bits x 22
// octaves, s in [2^-14, 2^8]). Kernel 2 does symmetric all-pairs
// acc[i] = sum_j m(s_ij)*(p_j - p_i)  (j==i term is exactly 0), via a
// per-interval (slope,intercept) LDS table: one ds_read_b64 + fma per pair.
// R7 FAILED: atomic cost scales with NSPLIT (~5us @32). R8: partials+reduce
// kernel only -1us (1.6MB round-trip + extra dispatch ate the gain).
// R9: in-block j-split reduction. Block = 16 i x 32 splits (512 thr); after
// the 64-j loop, 2x shfl_xor collapses the 4 splits within each wave, one
// small LDS pass collapses the 8 waves, direct store to out. No partials,
// no reduce kernel, no atomics, no out-zeroing. Same 256-block geometry.

#define EPS2      1.0e-4f
#define TAB_BITS  6
#define TAB_SHIFT (23 - TAB_BITS)            // 17
#define TAB_EMIN  113                        // biased exponent of 2^-14
#define TAB_BASE  (TAB_EMIN << TAB_BITS)     // 7232
#define TAB_OCT   22                         // 2^-14 .. 2^8
#define TAB_N     (TAB_OCT << TAB_BITS)      // 1408 intervals

#define NPART  2048
#define BLOCK  512
#define WI     16                            // i-particles per block
#define NSPL   (BLOCK / WI)                  // 32 j-splits inside the block
#define JPT    (NPART / NSPL)                // 64 j per thread

// ---- table build: 64 threads/entry, one output channel per lane ----------
// W2[k*64 + lane] is a coalesced 256B/wave load; W1/b1 are wave-uniform.
__global__ void build_table(const float* __restrict__ W1, const float* __restrict__ b1,
                            const float* __restrict__ W2, const float* __restrict__ b2,
                            const float* __restrict__ W3, const float* __restrict__ b3,
                            float* __restrict__ tab) {
    const int t = blockIdx.x * blockDim.x + threadIdx.x;
    const int entry = t >> 6;
    const int o     = t & 63;                // output channel == lane
    if (entry > TAB_N) return;

    const unsigned u = (unsigned)(entry + TAB_BASE) << TAB_SHIFT;
    const float s = __uint_as_float(u);      // exact sample point
    const float d = sqrtf(s);
    const float idc = 1.0f / (s * d);

    float acc = b2[o];
#pragma unroll
    for (int k = 0; k < 64; ++k) {
        float hv = fmaf(d, W1[k], fmaf(idc, W1[64 + k], b1[k]));
        hv = hv > 0.0f ? hv : 0.0f;
        acc = fmaf(hv, W2[k * 64 + o], acc);
    }
    float part = (acc > 0.0f ? acc : 0.0f) * W3[o];

    part += __shfl_down(part, 32, 64);
    part += __shfl_down(part, 16, 64);
    part += __shfl_down(part, 8, 64);
    part += __shfl_down(part, 4, 64);
    part += __shfl_down(part, 2, 64);
    part += __shfl_down(part, 1, 64);
    if (o == 0) tab[entry] = part + b3[0];
}

// ---------------- all-pairs force accumulation -----------------------------
// thread (s, il): s = tid>>4 (j-split), il = tid&15 (local i). Lane layout:
// lane = s_local*16 + il with s_local = lane>>4, so the 4 splits sharing a
// wave differ only in lane bits 4,5 -> shfl_xor(16), shfl_xor(32) reduce.
__global__ __launch_bounds__(BLOCK, 4)
void forces(const float* __restrict__ pos, const float* __restrict__ tab,
            float* __restrict__ out) {
    __shared__ float2 tabs[TAB_N + 1];       // (slope, intercept): 11272 B
    __shared__ float red[BLOCK / 64][WI][3]; // 8 waves x 16 i x 3: 1536 B

    const int tid = threadIdx.x;

    // stage table as (a,b): m(s) = a*s + b on each interval. Interval width
    // is an exact power of 2 -> reciprocal by exponent arithmetic.
    for (int k = tid; k < TAB_N; k += BLOCK) {
        float t0 = tab[k], t1 = tab[k + 1];
        float s0 = __uint_as_float((unsigned)(k + TAB_BASE) << TAB_SHIFT);
        float rcpw = __uint_as_float((unsigned)(147 - (k >> TAB_BITS)) << 23);
        float a = (t1 - t0) * rcpw;
        tabs[k] = make_float2(a, fmaf(-a, s0, t0));
    }
    __syncthreads();

    const int bx = blockIdx.x;               // i-chunk: 0..127
    const int b  = blockIdx.y;               // batch
    const int il = tid & (WI - 1);
    const int sp = tid >> 4;                 // 0..31
    const int i  = bx * WI + il;

    const float* posb = pos + (size_t)b * NPART * 3;
    const float pix = posb[i * 3 + 0];
    const float piy = posb[i * 3 + 1];
    const float piz = posb[i * 3 + 2];

    float ax = 0.0f, ay = 0.0f, az = 0.0f;
    const float* pj = posb + sp * JPT * 3;   // 4 distinct addrs/wave, L1-hot

#pragma unroll 8
    for (int jj = 0; jj < JPT; ++jj) {
        float dx = pj[jj * 3 + 0] - pix;
        float dy = pj[jj * 3 + 1] - piy;
        float dz = pj[jj * 3 + 2] - piz;
        float s = fmaf(dx, dx, fmaf(dy, dy, fmaf(dz, dz, EPS2)));
        // s >= EPS2 = 1e-4 > 2^-14 so no underflow; unsigned min clamps high.
        unsigned idx = (__float_as_uint(s) >> TAB_SHIFT) - TAB_BASE;
        idx = idx > TAB_N - 1u ? TAB_N - 1u : idx;
        float2 ab = tabs[idx];               // one ds_read_b64 gather
        float m = fmaf(s, ab.x, ab.y);
        ax = fmaf(m, dx, ax);
        ay = fmaf(m, dy, ay);
        az = fmaf(m, dz, az);
    }

    // collapse the 4 splits inside each wave (lane bits 4,5)
    ax += __shfl_xor(ax, 16, 64); ax += __shfl_xor(ax, 32, 64);
    ay += __shfl_xor(ay, 16, 64); ay += __shfl_xor(ay, 32, 64);
    az += __shfl_xor(az, 16, 64); az += __shfl_xor(az, 32, 64);

    const int lane = tid & 63;
    const int w    = tid >> 6;
    if (lane < WI) {
        red[w][lane][0] = ax;
        red[w][lane][1] = ay;
        red[w][lane][2] = az;
    }
    __syncthreads();

    // collapse the 8 waves; 48 threads each produce one output float
    if (tid < WI * 3) {
        const int ii = tid / 3;
        const int c  = tid - ii * 3;
        float sum = 0.0f;
#pragma unroll
        for (int w2 = 0; w2 < BLOCK / 64; ++w2) sum += red[w2][ii][c];
        out[((size_t)b * NPART + bx * WI + ii) * 3 + c] = sum;
    }
}

extern "C" void kernel_launch(void* const* d_in, const int* in_sizes, int n_in,
                              void* d_out, int out_size, void* d_ws, size_t ws_size,
                              hipStream_t stream) {
    const float* pos = (const float*)d_in[0];
    const float* W1  = (const float*)d_in[1];
    const float* b1  = (const float*)d_in[2];
    const float* W2  = (const float*)d_in[3];
    const float* b2  = (const float*)d_in[4];
    const float* W3  = (const float*)d_in[5];
    const float* b3  = (const float*)d_in[6];
    float* out = (float*)d_out;
    float* tab = (float*)d_ws;               // (TAB_N+1) floats

    const int B = in_sizes[0] / (NPART * 3); // = 2

    const int build_threads = (TAB_N + 1) * 64;  // 90176
    build_table<<<(build_threads + 255) / 256, 256, 0, stream>>>(
        W1, b1, W2, b2, W3, b3, tab);

    forces<<<dim3(NPART / WI, B), BLOCK, 0, stream>>>(pos, tab, out);
}